// Round 4
// baseline (483.769 us; speedup 1.0000x reference)
//
#include <hip/hip_runtime.h>
#include <hip/hip_bf16.h>
#include <math.h>

#define EMBED 768
#define HEADS 12
#define HEAD_DIM 64
#define HIDDEN 3072
#define SEQ 1024
#define BATCH 8
#define TOKENS (SEQ*BATCH)

typedef unsigned short u16;
typedef __attribute__((ext_vector_type(8))) short bf16x8;
typedef __attribute__((ext_vector_type(4))) float floatx4;

__device__ __forceinline__ u16 f2bf(float f){
    union { float f; unsigned u; } v; v.f = f;
    unsigned r = v.u + 0x7fffu + ((v.u >> 16) & 1u);
    return (u16)(r >> 16);
}

__device__ __forceinline__ void gload16(const void* g, void* l){
    __builtin_amdgcn_global_load_lds((const __attribute__((address_space(1))) void*)g,
                                     (__attribute__((address_space(3))) void*)l, 16, 0, 0);
}

// fast GELU (tanh approx, sigmoid form): err ~1e-3 absolute, fine vs bf16 tolerance
__device__ __forceinline__ float gelu_fast(float x){
    float t = 1.5957691216f * (x + 0.044715f * x * x * x);  // 2*0.7978845608
    return x / (1.0f + __expf(-t));
}

// ---------------- weight cast+transpose: W (K x N) fp32 -> Wt (N x K) bf16 ----------------
__global__ void transpose_cast(const float* __restrict__ W, u16* __restrict__ Wt, int K, int N){
    __shared__ float tile[32][33];
    int n0 = blockIdx.x * 32, k0 = blockIdx.y * 32;
    int tx = threadIdx.x, ty = threadIdx.y;  // 32 x 8
    #pragma unroll
    for(int i=0;i<32;i+=8) tile[ty+i][tx] = W[(size_t)(k0+ty+i)*N + n0+tx];
    __syncthreads();
    #pragma unroll
    for(int i=0;i<32;i+=8) Wt[(size_t)(n0+ty+i)*K + k0+tx] = f2bf(tile[tx][ty+i]);
}

// ---------------- layernorm: fp32 in -> bf16 out. one wave per row of 768 ----------------
__global__ __launch_bounds__(256) void ln_kernel(const float* __restrict__ x, const float* __restrict__ g,
                                                 const float* __restrict__ b, u16* __restrict__ out){
    int row  = blockIdx.x * 4 + (threadIdx.x >> 6);
    int lane = threadIdx.x & 63;
    const float* xr = x + (size_t)row * EMBED;
    float v[12];
    float s = 0.f;
    #pragma unroll
    for(int i=0;i<12;i++){ v[i] = xr[lane + i*64]; s += v[i]; }
    #pragma unroll
    for(int o=32;o>0;o>>=1) s += __shfl_xor(s, o);
    float mu = s * (1.0f/EMBED);
    float s2 = 0.f;
    #pragma unroll
    for(int i=0;i<12;i++){ float d = v[i]-mu; s2 += d*d; }
    #pragma unroll
    for(int o=32;o>0;o>>=1) s2 += __shfl_xor(s2, o);
    float rstd = rsqrtf(s2*(1.0f/EMBED) + 1e-5f);
    u16* orow = out + (size_t)row * EMBED;
    #pragma unroll
    for(int i=0;i<12;i++){
        int c = lane + i*64;
        orow[c] = f2bf((v[i]-mu)*rstd*g[c] + b[c]);
    }
}

// ---------------- GEMM: C(MxN) = A(MxK,bf16) @ Bt(NxK,bf16)^T ----------------
// EPI 0: [bias] -> bf16 (vectorized LDS-roundtrip epilogue)
// EPI 1: bias + fast GELU -> bf16 (vectorized LDS-roundtrip epilogue)
// EPI 2: bias + fp32 residual add -> fp32 (direct line-exact stores)
// K-loop LDS staging uses source-chunk XOR swizzle -> 2-way max bank aliasing (free).
template<int EPI>
__global__ __launch_bounds__(256) void gemm_bt(const u16* __restrict__ A, const u16* __restrict__ Bt,
        void* __restrict__ Cout, const float* __restrict__ bias, const float* __restrict__ res,
        int M, int N, int K, int ldc){
    __shared__ __align__(16) u16 SM[8192];      // 16 KB: As|Bs in K-loop, C-tile in epilogue
    u16* As = SM;
    u16* Bs = SM + 4096;
    int tid  = threadIdx.x;
    int wave = tid >> 6, lane = tid & 63;
    int quad = lane >> 4, lm = lane & 15;
    int m0 = blockIdx.y * 128, n0 = blockIdx.x * 128;
    int wm = (wave & 1) * 64, wn = (wave >> 1) * 64;

    floatx4 acc[4][4];
    #pragma unroll
    for(int i=0;i<4;i++)
        #pragma unroll
        for(int j=0;j<4;j++) acc[i][j] = (floatx4){0.f,0.f,0.f,0.f};

    int sr = tid >> 2;                          // 0..63 staging row
    int swc = (((tid & 3) ^ (sr & 3)) << 3);    // swizzled source chunk (u16 units)
    const u16* ga0 = A  + (size_t)(m0 + sr)      * K + swc;
    const u16* ga1 = A  + (size_t)(m0 + sr + 64) * K + swc;
    const u16* gb0 = Bt + (size_t)(n0 + sr)      * K + swc;
    const u16* gb1 = Bt + (size_t)(n0 + sr + 64) * K + swc;
    u16* lA0 = As + tid*8;
    u16* lA1 = As + 2048 + tid*8;
    u16* lB0 = Bs + tid*8;
    u16* lB1 = Bs + 2048 + tid*8;

    for(int k0=0; k0<K; k0+=32){
        __syncthreads();
        gload16(ga0 + k0, lA0);
        gload16(ga1 + k0, lA1);
        gload16(gb0 + k0, lB0);
        gload16(gb1 + k0, lB1);
        __syncthreads();
        bf16x8 af[4], bfr[4];
        #pragma unroll
        for(int i=0;i<4;i++){
            // LDS slot s holds chunk s^(row&3); want chunk=quad -> slot = quad^(row&3), row&3==lm&3
            af[i]  = *(const bf16x8*)(As + (wm + i*16 + lm)*32 + ((quad ^ (lm&3))<<3));
            bfr[i] = *(const bf16x8*)(Bs + (wn + i*16 + lm)*32 + ((quad ^ (lm&3))<<3));
        }
        #pragma unroll
        for(int mf=0;mf<4;mf++)
            #pragma unroll
            for(int nf=0;nf<4;nf++)
                acc[mf][nf] = __builtin_amdgcn_mfma_f32_16x16x32_bf16(af[mf], bfr[nf], acc[mf][nf], 0, 0, 0);
    }

    if(EPI == 2){
        // fp32 out: 16 lanes x 4B = exact 64B line per (nf,r) store
        #pragma unroll
        for(int nf=0;nf<4;nf++){
            int col = n0 + wn + nf*16 + lm;
            float bv = bias[col];
            #pragma unroll
            for(int mf=0;mf<4;mf++){
                int row0 = m0 + wm + mf*16 + quad*4;
                #pragma unroll
                for(int r=0;r<4;r++){
                    size_t idx = (size_t)(row0 + r) * ldc + col;
                    ((float*)Cout)[idx] = acc[mf][nf][r] + bv + res[idx];
                }
            }
        }
        return;
    }

    // bf16 out: LDS roundtrip -> coalesced dwordx4 stores, two 64-row passes
    #pragma unroll
    for(int p=0;p<2;p++){
        __syncthreads();
        if((wave & 1) == p){
            #pragma unroll
            for(int nf=0;nf<4;nf++){
                int col = wn + nf*16 + lm;           // 0..127 block-local
                float bv = bias ? bias[n0 + col] : 0.f;
                #pragma unroll
                for(int mf=0;mf<4;mf++){
                    #pragma unroll
                    for(int r=0;r<4;r++){
                        int row = mf*16 + quad*4 + r;  // 0..63 pass-local
                        float v = acc[mf][nf][r] + bv;
                        if(EPI == 1) v = gelu_fast(v);
                        int addr = row*128 + ((((col>>3) ^ (row&15))<<3)) + (col&7);
                        SM[addr] = f2bf(v);
                    }
                }
            }
        }
        __syncthreads();
        {
            int row = tid >> 2;                      // 0..63
            int cg  = tid & 3;                       // 32-col group
            u16* crow = (u16*)Cout + (size_t)(m0 + p*64 + row) * ldc + n0;
            #pragma unroll
            for(int j=0;j<4;j++){
                int chunk = cg*4 + j;                // 0..15
                int slot  = chunk ^ (row & 15);
                bf16x8 t = *(const bf16x8*)(SM + row*128 + slot*8);
                *(bf16x8*)(crow + chunk*8) = t;
            }
        }
    }
}

// ---------------- V transpose: qkv cols [1536..2304) -> vt[b][h][d][key] ----------------
__global__ __launch_bounds__(256) void v_transpose(const u16* __restrict__ qkv, u16* __restrict__ vt){
    __shared__ __align__(16) u16 T[64*72];   // [token-local][d], pad stride 72 (144B, 16B-aligned)
    int qt = blockIdx.x, h = blockIdx.y, b = blockIdx.z;
    int tid = threadIdx.x;
    {
        int row = tid >> 2;          // token-local 0..63
        int c   = tid & 3;           // 16-u16 chunk (32B)
        const u16* src = qkv + (size_t)(b*SEQ + qt*64 + row)*2304 + 1536 + h*64 + c*16;
        bf16x8 a = *(const bf16x8*)(src);
        bf16x8 bvec = *(const bf16x8*)(src + 8);
        *(bf16x8*)(T + row*72 + c*16)     = a;
        *(bf16x8*)(T + row*72 + c*16 + 8) = bvec;
    }
    __syncthreads();
    {
        int d  = tid >> 2;           // 0..63
        int kc = tid & 3;            // 16-key group
        bf16x8 o0, o1;
        #pragma unroll
        for(int i=0;i<8;i++)  o0[i] = (short)T[(kc*16 + i)*72 + d];
        #pragma unroll
        for(int i=0;i<8;i++)  o1[i] = (short)T[(kc*16 + 8 + i)*72 + d];
        u16* dst = vt + ((size_t)(b*HEADS + h)*64 + d)*SEQ + qt*64 + kc*16;
        *(bf16x8*)(dst)     = o0;
        *(bf16x8*)(dst + 8) = o1;
    }
}

// ---------------- flash attention: m97-style LDS staging ----------------
// qkv: (TOKENS x 2304) bf16 [Q|K|V]; vt: [b][h][d][key] bf16; out: (TOKENS x 768) bf16.
// grid (8,12,8), block 256 = 4 waves; block: 128 q-rows; wave: 32 rows (2 m-frags).
__global__ __launch_bounds__(256) void attn_kernel(const u16* __restrict__ qkv, const u16* __restrict__ vt,
                                                   u16* __restrict__ out){
    int qt = blockIdx.x, h = blockIdx.y, b = blockIdx.z;
    int tid = threadIdx.x;
    int wave = tid >> 6, lane = tid & 63;
    int quad = lane >> 4, lm = lane & 15;

    __shared__ __align__(16) u16 Ks[64*64];     // 8 KB, source-swizzled
    __shared__ __align__(16) u16 Vs[64*64];     // 8 KB, source-swizzled
    __shared__ __align__(16) u16 P[8][16*64];   // wave-private P tiles, 16 KB

    const u16* qbase = qkv + (size_t)b * SEQ * 2304;
    const u16* vbase = vt + (size_t)(b*HEADS + h) * 64 * SEQ;

    int q0 = qt*128 + wave*32;
    bf16x8 qf[2][2];
    #pragma unroll
    for(int mf=0;mf<2;mf++){
        const u16* qp = qbase + (size_t)(q0 + mf*16 + lm)*2304 + h*64;
        qf[mf][0] = *(const bf16x8*)(qp + quad*8);
        qf[mf][1] = *(const bf16x8*)(qp + 32 + quad*8);
    }

    float l_i[2][4];
    floatx4 o_acc[2][4];
    #pragma unroll
    for(int mf=0;mf<2;mf++){
        #pragma unroll
        for(int r=0;r<4;r++) l_i[mf][r] = 0.f;
        #pragma unroll
        for(int nf=0;nf<4;nf++) o_acc[mf][nf] = (floatx4){0.f,0.f,0.f,0.f};
    }

    int sr = lane >> 3;   // 0..7
    int sp = lane & 7;    // 0..7
    const float C = 0.18033688011112186f;  // 0.125 * log2(e)

    for(int kt=0; kt<16; kt++){
        __syncthreads();
        #pragma unroll
        for(int i=0;i<2;i++){
            int rr = wave*16 + i*8 + sr;
            int sw = (sp ^ (rr & 7)) * 8;
            gload16(qbase + (size_t)(kt*64 + rr)*2304 + 768 + h*64 + sw,
                    Ks + (wave*16 + i*8)*64 + lane*8);
            gload16(vbase + (size_t)rr*SEQ + kt*64 + sw,
                    Vs + (wave*16 + i*8)*64 + lane*8);
        }
        __syncthreads();

        floatx4 s[2][4];
        #pragma unroll
        for(int nf=0;nf<4;nf++){
            int krow = nf*16 + lm;
            bf16x8 k0 = *(const bf16x8*)(Ks + krow*64 + ((quad     ^ (lm&7))*8));
            bf16x8 k1 = *(const bf16x8*)(Ks + krow*64 + (((4+quad) ^ (lm&7))*8));
            #pragma unroll
            for(int mf=0;mf<2;mf++){
                floatx4 t = (floatx4){0.f,0.f,0.f,0.f};
                t = __builtin_amdgcn_mfma_f32_16x16x32_bf16(qf[mf][0], k0, t, 0, 0, 0);
                t = __builtin_amdgcn_mfma_f32_16x16x32_bf16(qf[mf][1], k1, t, 0, 0, 0);
                s[mf][nf] = t;
            }
        }

        #pragma unroll
        for(int mf=0;mf<2;mf++){
            u16* Pw = &P[wave*2+mf][0];
            #pragma unroll
            for(int r=0;r<4;r++){
                float sum = 0.f;
                #pragma unroll
                for(int nf=0;nf<4;nf++){
                    float e = exp2f(s[mf][nf][r]*C);
                    s[mf][nf][r] = e;
                    sum += e;
                }
                sum += __shfl_xor(sum, 1);
                sum += __shfl_xor(sum, 2);
                sum += __shfl_xor(sum, 4);
                sum += __shfl_xor(sum, 8);
                l_i[mf][r] += sum;
            }
            #pragma unroll
            for(int nf=0;nf<4;nf++){
                #pragma unroll
                for(int r=0;r<4;r++){
                    int row = quad*4 + r;
                    int key = nf*16 + lm;
                    int addr = row*64 + ((((key>>3) ^ row) & 7)<<3) + (key&7);
                    unsigned u = __builtin_bit_cast(unsigned, s[mf][nf][r]);
                    Pw[addr] = (u16)((u + 0x8000u) >> 16);
                }
            }
        }

        #pragma unroll
        for(int ks=0;ks<2;ks++){
            bf16x8 vf[4];
            #pragma unroll
            for(int nf=0;nf<4;nf++)
                vf[nf] = *(const bf16x8*)(Vs + (nf*16+lm)*64 + (((ks*4+quad) ^ (lm&7))*8));
            #pragma unroll
            for(int mf=0;mf<2;mf++){
                bf16x8 pa = *(const bf16x8*)(&P[wave*2+mf][0] + lm*64 + (((ks*4+quad) ^ (lm&7))*8));
                #pragma unroll
                for(int nf=0;nf<4;nf++)
                    o_acc[mf][nf] = __builtin_amdgcn_mfma_f32_16x16x32_bf16(pa, vf[nf], o_acc[mf][nf], 0, 0, 0);
            }
        }
    }

    #pragma unroll
    for(int mf=0;mf<2;mf++){
        int token = b*SEQ + qt*128 + wave*32 + mf*16 + quad*4;
        float rl[4];
        #pragma unroll
        for(int r=0;r<4;r++) rl[r] = 1.0f / l_i[mf][r];
        #pragma unroll
        for(int nf=0;nf<4;nf++){
            #pragma unroll
            for(int r=0;r<4;r++){
                out[(size_t)(token + r)*EMBED + h*64 + nf*16 + lm] = f2bf(o_acc[mf][nf][r] * rl[r]);
            }
        }
    }
}

extern "C" void kernel_launch(void* const* d_in, const int* in_sizes, int n_in,
                              void* d_out, int out_size, void* d_ws, size_t ws_size,
                              hipStream_t stream) {
    const float* x      = (const float*)d_in[0];
    const float* g1     = (const float*)d_in[1];
    const float* b1     = (const float*)d_in[2];
    const float* g2     = (const float*)d_in[3];
    const float* b2     = (const float*)d_in[4];
    const float* w_qkv  = (const float*)d_in[5];
    const float* w_proj = (const float*)d_in[6];
    const float* b_proj = (const float*)d_in[7];
    const float* w_fc1  = (const float*)d_in[8];
    const float* b_fc1  = (const float*)d_in[9];
    const float* w_fc2  = (const float*)d_in[10];
    const float* b_fc2  = (const float*)d_in[11];
    float* out = (float*)d_out;

    char* ws = (char*)d_ws;
    // layout (bytes), total 102,236,160 (same as round 3):
    u16*   wqkv_t  = (u16*)  (ws + 0);          //  2304x768 bf16 -> 3,538,944
    u16*   wproj_t = (u16*)  (ws + 3538944);    //   768x768 bf16 -> 1,179,648
    u16*   wfc1_t  = (u16*)  (ws + 4718592);    //  3072x768 bf16 -> 4,718,592
    u16*   wfc2_t  = (u16*)  (ws + 9437184);    //  768x3072 bf16 -> 4,718,592
    float* x1      = (float*)(ws + 14155776);   //  8192x768 fp32 -> 25,165,824
    u16*   hbuf    = (u16*)  (ws + 39321600);   //  8192x768 bf16 -> 12,582,912
    u16*   qkvbuf  = (u16*)  (ws + 51904512);   // 8192x2304 bf16 -> 37,748,736
    u16*   attn_o  = (u16*)  (ws + 89653248);   //  8192x768 bf16 -> 12,582,912 (end 102,236,160)
    // aliases (disjoint lifetimes):
    u16*   vtbuf   = hbuf;    // vt written after qkv GEMM consumed hbuf; dead before ln2 rewrites hbuf
    u16*   h2      = hbuf;    // ln2 output (after attn read vt)
    u16*   fc1_o   = qkvbuf;  // fc1 output 50,331,648 B == qkvbuf+attn_o region; both dead by then

    dim3 tb(32, 8);
    transpose_cast<<<dim3(2304/32,  768/32), tb, 0, stream>>>(w_qkv,  wqkv_t,  768, 2304);
    transpose_cast<<<dim3( 768/32,  768/32), tb, 0, stream>>>(w_proj, wproj_t, 768,  768);
    transpose_cast<<<dim3(3072/32,  768/32), tb, 0, stream>>>(w_fc1,  wfc1_t,  768, 3072);
    transpose_cast<<<dim3( 768/32, 3072/32), tb, 0, stream>>>(w_fc2,  wfc2_t, 3072,  768);

    ln_kernel<<<TOKENS/4, 256, 0, stream>>>(x, g1, b1, hbuf);

    gemm_bt<0><<<dim3(2304/128, TOKENS/128), 256, 0, stream>>>(hbuf, wqkv_t, qkvbuf, nullptr, nullptr, TOKENS, 2304, 768, 2304);

    v_transpose<<<dim3(SEQ/64, HEADS, BATCH), 256, 0, stream>>>(qkvbuf, vtbuf);

    attn_kernel<<<dim3(8, HEADS, BATCH), 256, 0, stream>>>(qkvbuf, vtbuf, attn_o);

    gemm_bt<2><<<dim3( 768/128, TOKENS/128), 256, 0, stream>>>(attn_o, wproj_t, x1, b_proj, x, TOKENS, 768, 768, 768);

    ln_kernel<<<TOKENS/4, 256, 0, stream>>>(x1, g2, b2, h2);

    gemm_bt<1><<<dim3(3072/128, TOKENS/128), 256, 0, stream>>>(h2, wfc1_t, fc1_o, b_fc1, nullptr, TOKENS, 3072, 768, 3072);

    gemm_bt<2><<<dim3( 768/128, TOKENS/128), 256, 0, stream>>>(fc1_o, wfc2_t, out, b_fc2, x1, TOKENS, 768, 3072, 768);
}

// Round 5
// 411.617 us; speedup vs baseline: 1.1753x; 1.1753x over previous
//
#include <hip/hip_runtime.h>
#include <hip/hip_bf16.h>
#include <math.h>

#define EMBED 768
#define HEADS 12
#define HEAD_DIM 64
#define HIDDEN 3072
#define SEQ 1024
#define BATCH 8
#define TOKENS (SEQ*BATCH)

typedef unsigned short u16;
typedef __attribute__((ext_vector_type(8))) short bf16x8;
typedef __attribute__((ext_vector_type(4))) float floatx4;
typedef __attribute__((ext_vector_type(4))) u16 u16x4;

__device__ __forceinline__ u16 f2bf(float f){
    union { float f; unsigned u; } v; v.f = f;
    unsigned r = v.u + 0x7fffu + ((v.u >> 16) & 1u);
    return (u16)(r >> 16);
}

__device__ __forceinline__ void gload16(const void* g, void* l){
    __builtin_amdgcn_global_load_lds((const __attribute__((address_space(1))) void*)g,
                                     (__attribute__((address_space(3))) void*)l, 16, 0, 0);
}

// fast GELU (tanh approx, sigmoid form): abs err ~1e-3, fine vs 0.109 threshold
__device__ __forceinline__ float gelu_fast(float x){
    float t = 1.5957691216f * (x + 0.044715f * x * x * x);
    return x / (1.0f + __expf(-t));
}

// ---------------- weight cast+transpose: W (K x N) fp32 -> Wt (N x K) bf16 ----------------
__global__ void transpose_cast(const float* __restrict__ W, u16* __restrict__ Wt, int K, int N){
    __shared__ float tile[32][33];
    int n0 = blockIdx.x * 32, k0 = blockIdx.y * 32;
    int tx = threadIdx.x, ty = threadIdx.y;  // 32 x 8
    #pragma unroll
    for(int i=0;i<32;i+=8) tile[ty+i][tx] = W[(size_t)(k0+ty+i)*N + n0+tx];
    __syncthreads();
    #pragma unroll
    for(int i=0;i<32;i+=8) Wt[(size_t)(n0+ty+i)*K + k0+tx] = f2bf(tile[tx][ty+i]);
}

// ---------------- layernorm: fp32 in -> bf16 out. one wave per row of 768 ----------------
__global__ __launch_bounds__(256) void ln_kernel(const float* __restrict__ x, const float* __restrict__ g,
                                                 const float* __restrict__ b, u16* __restrict__ out){
    int row  = blockIdx.x * 4 + (threadIdx.x >> 6);
    int lane = threadIdx.x & 63;
    const float* xr = x + (size_t)row * EMBED;
    float v[12];
    float s = 0.f;
    #pragma unroll
    for(int i=0;i<12;i++){ v[i] = xr[lane + i*64]; s += v[i]; }
    #pragma unroll
    for(int o=32;o>0;o>>=1) s += __shfl_xor(s, o);
    float mu = s * (1.0f/EMBED);
    float s2 = 0.f;
    #pragma unroll
    for(int i=0;i<12;i++){ float d = v[i]-mu; s2 += d*d; }
    #pragma unroll
    for(int o=32;o>0;o>>=1) s2 += __shfl_xor(s2, o);
    float rstd = rsqrtf(s2*(1.0f/EMBED) + 1e-5f);
    u16* orow = out + (size_t)row * EMBED;
    #pragma unroll
    for(int i=0;i<12;i++){
        int c = lane + i*64;
        orow[c] = f2bf((v[i]-mu)*rstd*g[c] + b[c]);
    }
}

// ---------------- GEMM: C(MxN) = A(MxK,bf16) @ Bt(NxK,bf16)^T ----------------
// BK=64 K-tiles, split-panel LDS [ks][128 rows][32 cols] (frag reads byte-identical to m97 pattern).
// EPI 0: [bias] -> bf16.  EPI 1: bias + fast GELU -> bf16.  EPI 2: bias + fp32 residual -> fp32.
// EPI 3: qkv: cols<1536 -> bf16 Cout (ldc=1536); cols>=1536 -> V transposed to vt[b][h][d][key].
template<int EPI>
__global__ __launch_bounds__(256) void gemm_bt(const u16* __restrict__ A, const u16* __restrict__ Bt,
        void* __restrict__ Cout, const float* __restrict__ bias, const float* __restrict__ res,
        u16* __restrict__ vt, int M, int N, int K, int ldc){
    __shared__ __align__(16) u16 As[8192];   // 16 KB: [ks][row][32]
    __shared__ __align__(16) u16 Bs[8192];   // 16 KB
    int tid  = threadIdx.x;
    int wave = tid >> 6, lane = tid & 63;
    int quad = lane >> 4, lm = lane & 15;
    int m0 = blockIdx.y * 128, n0 = blockIdx.x * 128;
    int wm = (wave & 1) * 64, wn = (wave >> 1) * 64;

    floatx4 acc[4][4];
    #pragma unroll
    for(int i=0;i<4;i++)
        #pragma unroll
        for(int j=0;j<4;j++) acc[i][j] = (floatx4){0.f,0.f,0.f,0.f};

    int sr = tid >> 2;          // 0..63 staging row (within half)
    int sc = (tid & 3) * 8;     // 16B chunk within 32-col panel
    const u16* ga0 = A  + (size_t)(m0 + sr)      * K + sc;
    const u16* ga1 = A  + (size_t)(m0 + sr + 64) * K + sc;
    const u16* gb0 = Bt + (size_t)(n0 + sr)      * K + sc;
    const u16* gb1 = Bt + (size_t)(n0 + sr + 64) * K + sc;
    // dest decomposition: i*2048 + tid*8  ->  panel (i>>1), row (i&1)*64 + (tid>>2), chunk (tid&3)
    u16* lA0 = As + tid*8;          // i=0: row half 0, k half 0
    u16* lA1 = As + 2048 + tid*8;   // i=1: row half 1, k half 0
    u16* lA2 = As + 4096 + tid*8;   // i=2: row half 0, k half 1
    u16* lA3 = As + 6144 + tid*8;   // i=3: row half 1, k half 1
    u16* lB0 = Bs + tid*8;
    u16* lB1 = Bs + 2048 + tid*8;
    u16* lB2 = Bs + 4096 + tid*8;
    u16* lB3 = Bs + 6144 + tid*8;

    for(int k0=0; k0<K; k0+=64){
        __syncthreads();
        gload16(ga0 + k0,      lA0);
        gload16(ga1 + k0,      lA1);
        gload16(ga0 + k0 + 32, lA2);
        gload16(ga1 + k0 + 32, lA3);
        gload16(gb0 + k0,      lB0);
        gload16(gb1 + k0,      lB1);
        gload16(gb0 + k0 + 32, lB2);
        gload16(gb1 + k0 + 32, lB3);
        __syncthreads();
        #pragma unroll
        for(int ks=0;ks<2;ks++){
            bf16x8 af[4], bfr[4];
            #pragma unroll
            for(int i=0;i<4;i++){
                af[i]  = *(const bf16x8*)(As + ks*4096 + (wm + i*16 + lm)*32 + quad*8);
                bfr[i] = *(const bf16x8*)(Bs + ks*4096 + (wn + i*16 + lm)*32 + quad*8);
            }
            #pragma unroll
            for(int mf=0;mf<4;mf++)
                #pragma unroll
                for(int nf=0;nf<4;nf++)
                    acc[mf][nf] = __builtin_amdgcn_mfma_f32_16x16x32_bf16(af[mf], bfr[nf], acc[mf][nf], 0, 0, 0);
        }
    }

    if(EPI == 3 && n0 >= 1536){
        // V columns -> vt[((b*12+h)*64+d)*1024 + key], 4 consecutive keys per 8B store
        #pragma unroll
        for(int nf=0;nf<4;nf++){
            int col = n0 + wn + nf*16 + lm;
            int hh = (col - 1536) >> 6;
            int d  = col & 63;
            #pragma unroll
            for(int mf=0;mf<4;mf++){
                int row0 = m0 + wm + mf*16 + quad*4;
                int bb  = row0 >> 10;
                int key = row0 & 1023;
                u16x4 pk;
                #pragma unroll
                for(int r=0;r<4;r++) pk[r] = f2bf(acc[mf][nf][r]);
                *(u16x4*)(vt + ((size_t)(bb*HEADS+hh)*64 + d)*SEQ + key) = pk;
            }
        }
        return;
    }

    #pragma unroll
    for(int nf=0;nf<4;nf++){
        int col = n0 + wn + nf*16 + lm;
        float bv = bias ? bias[col] : 0.f;
        #pragma unroll
        for(int mf=0;mf<4;mf++){
            int row0 = m0 + wm + mf*16 + quad*4;
            #pragma unroll
            for(int r=0;r<4;r++){
                float v = acc[mf][nf][r] + bv;
                size_t idx = (size_t)(row0 + r) * ldc + col;
                if(EPI == 1){
                    v = gelu_fast(v);
                    ((u16*)Cout)[idx] = f2bf(v);
                } else if(EPI == 2){
                    ((float*)Cout)[idx] = v + res[idx];
                } else {
                    ((u16*)Cout)[idx] = f2bf(v);
                }
            }
        }
    }
}

// ---------------- flash attention (round-3 proven): m97-style LDS staging ----------------
// qk: (TOKENS x 1536) bf16 [Q | K]; vt: [b][h][d][key] bf16; out: (TOKENS x 768) bf16.
// grid (8,12,8), block 256 = 4 waves; block: 128 q-rows; wave: 32 rows (2 m-frags).
__global__ __launch_bounds__(256) void attn_kernel(const u16* __restrict__ qk, const u16* __restrict__ vt,
                                                   u16* __restrict__ out){
    int qt = blockIdx.x, h = blockIdx.y, b = blockIdx.z;
    int tid = threadIdx.x;
    int wave = tid >> 6, lane = tid & 63;
    int quad = lane >> 4, lm = lane & 15;

    __shared__ __align__(16) u16 Ks[64*64];
    __shared__ __align__(16) u16 Vs[64*64];
    __shared__ __align__(16) u16 P[8][16*64];

    const u16* qbase = qk + (size_t)b * SEQ * 1536;
    const u16* vbase = vt + (size_t)(b*HEADS + h) * 64 * SEQ;

    int q0 = qt*128 + wave*32;
    bf16x8 qf[2][2];
    #pragma unroll
    for(int mf=0;mf<2;mf++){
        const u16* qp = qbase + (size_t)(q0 + mf*16 + lm)*1536 + h*64;
        qf[mf][0] = *(const bf16x8*)(qp + quad*8);
        qf[mf][1] = *(const bf16x8*)(qp + 32 + quad*8);
    }

    float l_i[2][4];
    floatx4 o_acc[2][4];
    #pragma unroll
    for(int mf=0;mf<2;mf++){
        #pragma unroll
        for(int r=0;r<4;r++) l_i[mf][r] = 0.f;
        #pragma unroll
        for(int nf=0;nf<4;nf++) o_acc[mf][nf] = (floatx4){0.f,0.f,0.f,0.f};
    }

    int sr = lane >> 3;   // 0..7
    int sp = lane & 7;    // 0..7
    const float C = 0.18033688011112186f;  // 0.125 * log2(e)

    for(int kt=0; kt<16; kt++){
        __syncthreads();
        #pragma unroll
        for(int i=0;i<2;i++){
            int rr = wave*16 + i*8 + sr;
            int sw = (sp ^ (rr & 7)) * 8;
            gload16(qbase + (size_t)(kt*64 + rr)*1536 + 768 + h*64 + sw,
                    Ks + (wave*16 + i*8)*64 + lane*8);
            gload16(vbase + (size_t)rr*SEQ + kt*64 + sw,
                    Vs + (wave*16 + i*8)*64 + lane*8);
        }
        __syncthreads();

        floatx4 s[2][4];
        #pragma unroll
        for(int nf=0;nf<4;nf++){
            int krow = nf*16 + lm;
            bf16x8 k0 = *(const bf16x8*)(Ks + krow*64 + ((quad     ^ (lm&7))*8));
            bf16x8 k1 = *(const bf16x8*)(Ks + krow*64 + (((4+quad) ^ (lm&7))*8));
            #pragma unroll
            for(int mf=0;mf<2;mf++){
                floatx4 t = (floatx4){0.f,0.f,0.f,0.f};
                t = __builtin_amdgcn_mfma_f32_16x16x32_bf16(qf[mf][0], k0, t, 0, 0, 0);
                t = __builtin_amdgcn_mfma_f32_16x16x32_bf16(qf[mf][1], k1, t, 0, 0, 0);
                s[mf][nf] = t;
            }
        }

        #pragma unroll
        for(int mf=0;mf<2;mf++){
            u16* Pw = &P[wave*2+mf][0];
            #pragma unroll
            for(int r=0;r<4;r++){
                float sum = 0.f;
                #pragma unroll
                for(int nf=0;nf<4;nf++){
                    float e = exp2f(s[mf][nf][r]*C);
                    s[mf][nf][r] = e;
                    sum += e;
                }
                sum += __shfl_xor(sum, 1);
                sum += __shfl_xor(sum, 2);
                sum += __shfl_xor(sum, 4);
                sum += __shfl_xor(sum, 8);
                l_i[mf][r] += sum;
            }
            #pragma unroll
            for(int nf=0;nf<4;nf++){
                #pragma unroll
                for(int r=0;r<4;r++){
                    int row = quad*4 + r;
                    int key = nf*16 + lm;
                    int addr = row*64 + ((((key>>3) ^ row) & 7)<<3) + (key&7);
                    unsigned u = __builtin_bit_cast(unsigned, s[mf][nf][r]);
                    Pw[addr] = (u16)((u + 0x8000u) >> 16);
                }
            }
        }

        #pragma unroll
        for(int ks=0;ks<2;ks++){
            bf16x8 vf[4];
            #pragma unroll
            for(int nf=0;nf<4;nf++)
                vf[nf] = *(const bf16x8*)(Vs + (nf*16+lm)*64 + (((ks*4+quad) ^ (lm&7))*8));
            #pragma unroll
            for(int mf=0;mf<2;mf++){
                bf16x8 pa = *(const bf16x8*)(&P[wave*2+mf][0] + lm*64 + (((ks*4+quad) ^ (lm&7))*8));
                #pragma unroll
                for(int nf=0;nf<4;nf++)
                    o_acc[mf][nf] = __builtin_amdgcn_mfma_f32_16x16x32_bf16(pa, vf[nf], o_acc[mf][nf], 0, 0, 0);
            }
        }
    }

    #pragma unroll
    for(int mf=0;mf<2;mf++){
        int token = b*SEQ + qt*128 + wave*32 + mf*16 + quad*4;
        float rl[4];
        #pragma unroll
        for(int r=0;r<4;r++) rl[r] = 1.0f / l_i[mf][r];
        #pragma unroll
        for(int nf=0;nf<4;nf++){
            #pragma unroll
            for(int r=0;r<4;r++){
                out[(size_t)(token + r)*EMBED + h*64 + nf*16 + lm] = f2bf(o_acc[mf][nf][r] * rl[r]);
            }
        }
    }
}

extern "C" void kernel_launch(void* const* d_in, const int* in_sizes, int n_in,
                              void* d_out, int out_size, void* d_ws, size_t ws_size,
                              hipStream_t stream) {
    const float* x      = (const float*)d_in[0];
    const float* g1     = (const float*)d_in[1];
    const float* b1     = (const float*)d_in[2];
    const float* g2     = (const float*)d_in[3];
    const float* b2     = (const float*)d_in[4];
    const float* w_qkv  = (const float*)d_in[5];
    const float* w_proj = (const float*)d_in[6];
    const float* b_proj = (const float*)d_in[7];
    const float* w_fc1  = (const float*)d_in[8];
    const float* b_fc1  = (const float*)d_in[9];
    const float* w_fc2  = (const float*)d_in[10];
    const float* b_fc2  = (const float*)d_in[11];
    float* out = (float*)d_out;

    char* ws = (char*)d_ws;
    // layout (bytes), total 102,236,160 (round-3 proven):
    u16*   wqkv_t  = (u16*)  (ws + 0);          //  2304x768 bf16 -> 3,538,944
    u16*   wproj_t = (u16*)  (ws + 3538944);    //   768x768 bf16 -> 1,179,648
    u16*   wfc1_t  = (u16*)  (ws + 4718592);    //  3072x768 bf16 -> 4,718,592
    u16*   wfc2_t  = (u16*)  (ws + 9437184);    //  768x3072 bf16 -> 4,718,592
    float* x1      = (float*)(ws + 14155776);   //  8192x768 fp32 -> 25,165,824
    u16*   hbuf    = (u16*)  (ws + 39321600);   //  8192x768 bf16 -> 12,582,912
    u16*   qkbuf   = (u16*)  (ws + 51904512);   // 8192x1536 bf16 -> 25,165,824
    u16*   vtbuf   = (u16*)  (ws + 77070336);   // 8x12x64x1024   -> 12,582,912
    u16*   attn_o  = (u16*)  (ws + 89653248);   //  8192x768 bf16 -> 12,582,912 (end 102,236,160)
    u16*   fc1_o   = qkbuf;  // alias: qk+vt+attn_o = 50,331,648 B exactly, lifetimes disjoint
    u16*   h2      = hbuf;   // alias: h dead after qkv GEMM

    dim3 tb(32, 8);
    transpose_cast<<<dim3(2304/32,  768/32), tb, 0, stream>>>(w_qkv,  wqkv_t,  768, 2304);
    transpose_cast<<<dim3( 768/32,  768/32), tb, 0, stream>>>(w_proj, wproj_t, 768,  768);
    transpose_cast<<<dim3(3072/32,  768/32), tb, 0, stream>>>(w_fc1,  wfc1_t,  768, 3072);
    transpose_cast<<<dim3( 768/32, 3072/32), tb, 0, stream>>>(w_fc2,  wfc2_t, 3072,  768);

    ln_kernel<<<TOKENS/4, 256, 0, stream>>>(x, g1, b1, hbuf);

    gemm_bt<3><<<dim3(2304/128, TOKENS/128), 256, 0, stream>>>(hbuf, wqkv_t, qkbuf, nullptr, nullptr, vtbuf, TOKENS, 2304, 768, 1536);

    attn_kernel<<<dim3(8, HEADS, BATCH), 256, 0, stream>>>(qkbuf, vtbuf, attn_o);

    gemm_bt<2><<<dim3( 768/128, TOKENS/128), 256, 0, stream>>>(attn_o, wproj_t, x1, b_proj, x, nullptr, TOKENS, 768, 768, 768);

    ln_kernel<<<TOKENS/4, 256, 0, stream>>>(x1, g2, b2, h2);

    gemm_bt<1><<<dim3(3072/128, TOKENS/128), 256, 0, stream>>>(h2, wfc1_t, fc1_o, b_fc1, nullptr, nullptr, TOKENS, 3072, 768, 3072);

    gemm_bt<2><<<dim3( 768/128, TOKENS/128), 256, 0, stream>>>(fc1_o, wfc2_t, out, b_fc2, x1, nullptr, TOKENS, 768, 3072, 768);
}

// Round 7
// 393.050 us; speedup vs baseline: 1.2308x; 1.0472x over previous
//
#include <hip/hip_runtime.h>
#include <hip/hip_bf16.h>
#include <math.h>

#define EMBED 768
#define HEADS 12
#define HEAD_DIM 64
#define HIDDEN 3072
#define SEQ 1024
#define BATCH 8
#define TOKENS (SEQ*BATCH)

typedef unsigned short u16;
typedef __attribute__((ext_vector_type(8))) short bf16x8;
typedef __attribute__((ext_vector_type(4))) float floatx4;
typedef __attribute__((ext_vector_type(4))) u16 u16x4;

__device__ __forceinline__ u16 f2bf(float f){
    union { float f; unsigned u; } v; v.f = f;
    unsigned r = v.u + 0x7fffu + ((v.u >> 16) & 1u);
    return (u16)(r >> 16);
}

__device__ __forceinline__ void gload16(const void* g, void* l){
    __builtin_amdgcn_global_load_lds((const __attribute__((address_space(1))) void*)g,
                                     (__attribute__((address_space(3))) void*)l, 16, 0, 0);
}

// fast GELU (tanh approx, sigmoid form): abs err ~1e-3, fine vs 0.109 threshold
__device__ __forceinline__ float gelu_fast(float x){
    float t = 1.5957691216f * (x + 0.044715f * x * x * x);
    return x / (1.0f + __expf(-t));
}

// ---------------- weight cast+transpose: W (K x N) fp32 -> Wt (N x K) bf16 ----------------
__global__ void transpose_cast(const float* __restrict__ W, u16* __restrict__ Wt, int K, int N){
    __shared__ float tile[32][33];
    int n0 = blockIdx.x * 32, k0 = blockIdx.y * 32;
    int tx = threadIdx.x, ty = threadIdx.y;  // 32 x 8
    #pragma unroll
    for(int i=0;i<32;i+=8) tile[ty+i][tx] = W[(size_t)(k0+ty+i)*N + n0+tx];
    __syncthreads();
    #pragma unroll
    for(int i=0;i<32;i+=8) Wt[(size_t)(n0+ty+i)*K + k0+tx] = f2bf(tile[tx][ty+i]);
}

// ---------------- layernorm: fp32 in -> bf16 out. one wave per row of 768 ----------------
__global__ __launch_bounds__(256) void ln_kernel(const float* __restrict__ x, const float* __restrict__ g,
                                                 const float* __restrict__ b, u16* __restrict__ out){
    int row  = blockIdx.x * 4 + (threadIdx.x >> 6);
    int lane = threadIdx.x & 63;
    const float* xr = x + (size_t)row * EMBED;
    float v[12];
    float s = 0.f;
    #pragma unroll
    for(int i=0;i<12;i++){ v[i] = xr[lane + i*64]; s += v[i]; }
    #pragma unroll
    for(int o=32;o>0;o>>=1) s += __shfl_xor(s, o);
    float mu = s * (1.0f/EMBED);
    float s2 = 0.f;
    #pragma unroll
    for(int i=0;i<12;i++){ float d = v[i]-mu; s2 += d*d; }
    #pragma unroll
    for(int o=32;o>0;o>>=1) s2 += __shfl_xor(s2, o);
    float rstd = rsqrtf(s2*(1.0f/EMBED) + 1e-5f);
    u16* orow = out + (size_t)row * EMBED;
    #pragma unroll
    for(int i=0;i<12;i++){
        int c = lane + i*64;
        orow[c] = f2bf((v[i]-mu)*rstd*g[c] + b[c]);
    }
}

// ---------------- GEMM: C(MxN) = A(MxK,bf16) @ Bt(NxK,bf16)^T ----------------
// Tiles: BM x 128, BK=64. LDS row-major [row][64 u16] (128B stride) with source-XOR swizzle:
// staging thread (srow=tid>>3) carries source chunk (tid&7)^(srow&7) -> LDS[row][slot s] holds
// chunk s^(row&7); frag read slot = (ks*4+quad)^(lm&7). 2-way max bank aliasing (free; attn-proven).
// Panel p (32 rows) dest offset = p*2048 + tid*8   [round-6 bug was p*4096].
// EPI 1: bias + fast GELU -> bf16.  EPI 2: bias + fp32 residual -> fp32.
// EPI 3 (BM=128): qkv: cols<1536 -> bf16 Cout (ldc=1536); cols>=1536 -> V transposed to vt.
template<int EPI, int BM>
__global__ __launch_bounds__(256) void gemm_bt(const u16* __restrict__ A, const u16* __restrict__ Bt,
        void* __restrict__ Cout, const float* __restrict__ bias, const float* __restrict__ res,
        u16* __restrict__ vt, int M, int N, int K, int ldc){
    constexpr int MF = BM/32;                    // m-frags per wave (4 for BM=128, 2 for BM=64)
    __shared__ __align__(16) u16 As[BM*64];      // BM rows x 64 u16
    __shared__ __align__(16) u16 Bs[128*64];     // 128 rows x 64 u16
    int tid  = threadIdx.x;
    int wave = tid >> 6, lane = tid & 63;
    int quad = lane >> 4, lm = lane & 15;
    int m0 = blockIdx.y * BM, n0 = blockIdx.x * 128;
    int wm = (wave & 1) * (BM/2);
    int wn = (wave >> 1) * 64;

    floatx4 acc[MF][4];
    #pragma unroll
    for(int i=0;i<MF;i++)
        #pragma unroll
        for(int j=0;j<4;j++) acc[i][j] = (floatx4){0.f,0.f,0.f,0.f};

    int srow = tid >> 3;                         // 0..31 staging row within 32-row panel
    int scol = ((tid & 7) ^ (srow & 7)) * 8;     // swizzled source chunk (u16 units)
    const u16* aP[MF];
    const u16* bP[4];
    #pragma unroll
    for(int p=0;p<MF;p++) aP[p] = A  + (size_t)(m0 + p*32 + srow) * K + scol;
    #pragma unroll
    for(int p=0;p<4;p++)  bP[p] = Bt + (size_t)(n0 + p*32 + srow) * K + scol;

    for(int k0=0; k0<K; k0+=64){
        __syncthreads();
        #pragma unroll
        for(int p=0;p<MF;p++) gload16(aP[p] + k0, As + p*2048 + tid*8);
        #pragma unroll
        for(int p=0;p<4;p++)  gload16(bP[p] + k0, Bs + p*2048 + tid*8);
        __syncthreads();
        #pragma unroll
        for(int ks=0;ks<2;ks++){
            int slotoff = (((ks*4+quad) ^ (lm&7)) << 3);
            bf16x8 af[MF], bfr[4];
            #pragma unroll
            for(int i=0;i<MF;i++)
                af[i]  = *(const bf16x8*)(As + (wm + i*16 + lm)*64 + slotoff);
            #pragma unroll
            for(int i=0;i<4;i++)
                bfr[i] = *(const bf16x8*)(Bs + (wn + i*16 + lm)*64 + slotoff);
            #pragma unroll
            for(int mf=0;mf<MF;mf++)
                #pragma unroll
                for(int nf=0;nf<4;nf++)
                    acc[mf][nf] = __builtin_amdgcn_mfma_f32_16x16x32_bf16(af[mf], bfr[nf], acc[mf][nf], 0, 0, 0);
        }
    }

    if(EPI == 3 && n0 >= 1536){
        // V columns -> vt[((b*12+h)*64+d)*1024 + key], 4 consecutive keys per 8B store
        #pragma unroll
        for(int nf=0;nf<4;nf++){
            int col = n0 + wn + nf*16 + lm;
            int hh = (col - 1536) >> 6;
            int d  = col & 63;
            #pragma unroll
            for(int mf=0;mf<MF;mf++){
                int row0 = m0 + wm + mf*16 + quad*4;
                int bb  = row0 >> 10;
                int key = row0 & 1023;
                u16x4 pk;
                #pragma unroll
                for(int r=0;r<4;r++) pk[r] = f2bf(acc[mf][nf][r]);
                *(u16x4*)(vt + ((size_t)(bb*HEADS+hh)*64 + d)*SEQ + key) = pk;
            }
        }
        return;
    }

    #pragma unroll
    for(int nf=0;nf<4;nf++){
        int col = n0 + wn + nf*16 + lm;
        float bv = bias ? bias[col] : 0.f;
        #pragma unroll
        for(int mf=0;mf<MF;mf++){
            int row0 = m0 + wm + mf*16 + quad*4;
            #pragma unroll
            for(int r=0;r<4;r++){
                float v = acc[mf][nf][r] + bv;
                size_t idx = (size_t)(row0 + r) * ldc + col;
                if(EPI == 1){
                    v = gelu_fast(v);
                    ((u16*)Cout)[idx] = f2bf(v);
                } else if(EPI == 2){
                    ((float*)Cout)[idx] = v + res[idx];
                } else {
                    ((u16*)Cout)[idx] = f2bf(v);
                }
            }
        }
    }
}

// ---------------- flash attention (round-3 proven): m97-style LDS staging ----------------
// qk: (TOKENS x 1536) bf16 [Q | K]; vt: [b][h][d][key] bf16; out: (TOKENS x 768) bf16.
// grid (8,12,8), block 256 = 4 waves; block: 128 q-rows; wave: 32 rows (2 m-frags).
__global__ __launch_bounds__(256) void attn_kernel(const u16* __restrict__ qk, const u16* __restrict__ vt,
                                                   u16* __restrict__ out){
    int qt = blockIdx.x, h = blockIdx.y, b = blockIdx.z;
    int tid = threadIdx.x;
    int wave = tid >> 6, lane = tid & 63;
    int quad = lane >> 4, lm = lane & 15;

    __shared__ __align__(16) u16 Ks[64*64];
    __shared__ __align__(16) u16 Vs[64*64];
    __shared__ __align__(16) u16 P[8][16*64];

    const u16* qbase = qk + (size_t)b * SEQ * 1536;
    const u16* vbase = vt + (size_t)(b*HEADS + h) * 64 * SEQ;

    int q0 = qt*128 + wave*32;
    bf16x8 qf[2][2];
    #pragma unroll
    for(int mf=0;mf<2;mf++){
        const u16* qp = qbase + (size_t)(q0 + mf*16 + lm)*1536 + h*64;
        qf[mf][0] = *(const bf16x8*)(qp + quad*8);
        qf[mf][1] = *(const bf16x8*)(qp + 32 + quad*8);
    }

    float l_i[2][4];
    floatx4 o_acc[2][4];
    #pragma unroll
    for(int mf=0;mf<2;mf++){
        #pragma unroll
        for(int r=0;r<4;r++) l_i[mf][r] = 0.f;
        #pragma unroll
        for(int nf=0;nf<4;nf++) o_acc[mf][nf] = (floatx4){0.f,0.f,0.f,0.f};
    }

    int sr = lane >> 3;   // 0..7
    int sp = lane & 7;    // 0..7
    const float C = 0.18033688011112186f;  // 0.125 * log2(e)

    for(int kt=0; kt<16; kt++){
        __syncthreads();
        #pragma unroll
        for(int i=0;i<2;i++){
            int rr = wave*16 + i*8 + sr;
            int sw = (sp ^ (rr & 7)) * 8;
            gload16(qbase + (size_t)(kt*64 + rr)*1536 + 768 + h*64 + sw,
                    Ks + (wave*16 + i*8)*64 + lane*8);
            gload16(vbase + (size_t)rr*SEQ + kt*64 + sw,
                    Vs + (wave*16 + i*8)*64 + lane*8);
        }
        __syncthreads();

        floatx4 s[2][4];
        #pragma unroll
        for(int nf=0;nf<4;nf++){
            int krow = nf*16 + lm;
            bf16x8 k0 = *(const bf16x8*)(Ks + krow*64 + ((quad     ^ (lm&7))*8));
            bf16x8 k1 = *(const bf16x8*)(Ks + krow*64 + (((4+quad) ^ (lm&7))*8));
            #pragma unroll
            for(int mf=0;mf<2;mf++){
                floatx4 t = (floatx4){0.f,0.f,0.f,0.f};
                t = __builtin_amdgcn_mfma_f32_16x16x32_bf16(qf[mf][0], k0, t, 0, 0, 0);
                t = __builtin_amdgcn_mfma_f32_16x16x32_bf16(qf[mf][1], k1, t, 0, 0, 0);
                s[mf][nf] = t;
            }
        }

        #pragma unroll
        for(int mf=0;mf<2;mf++){
            u16* Pw = &P[wave*2+mf][0];
            #pragma unroll
            for(int r=0;r<4;r++){
                float sum = 0.f;
                #pragma unroll
                for(int nf=0;nf<4;nf++){
                    float e = exp2f(s[mf][nf][r]*C);
                    s[mf][nf][r] = e;
                    sum += e;
                }
                sum += __shfl_xor(sum, 1);
                sum += __shfl_xor(sum, 2);
                sum += __shfl_xor(sum, 4);
                sum += __shfl_xor(sum, 8);
                l_i[mf][r] += sum;
            }
            #pragma unroll
            for(int nf=0;nf<4;nf++){
                #pragma unroll
                for(int r=0;r<4;r++){
                    int row = quad*4 + r;
                    int key = nf*16 + lm;
                    int addr = row*64 + ((((key>>3) ^ row) & 7)<<3) + (key&7);
                    unsigned u = __builtin_bit_cast(unsigned, s[mf][nf][r]);
                    Pw[addr] = (u16)((u + 0x8000u) >> 16);
                }
            }
        }

        #pragma unroll
        for(int ks=0;ks<2;ks++){
            bf16x8 vf[4];
            #pragma unroll
            for(int nf=0;nf<4;nf++)
                vf[nf] = *(const bf16x8*)(Vs + (nf*16+lm)*64 + (((ks*4+quad) ^ (lm&7))*8));
            #pragma unroll
            for(int mf=0;mf<2;mf++){
                bf16x8 pa = *(const bf16x8*)(&P[wave*2+mf][0] + lm*64 + (((ks*4+quad) ^ (lm&7))*8));
                #pragma unroll
                for(int nf=0;nf<4;nf++)
                    o_acc[mf][nf] = __builtin_amdgcn_mfma_f32_16x16x32_bf16(pa, vf[nf], o_acc[mf][nf], 0, 0, 0);
            }
        }
    }

    #pragma unroll
    for(int mf=0;mf<2;mf++){
        int token = b*SEQ + qt*128 + wave*32 + mf*16 + quad*4;
        float rl[4];
        #pragma unroll
        for(int r=0;r<4;r++) rl[r] = 1.0f / l_i[mf][r];
        #pragma unroll
        for(int nf=0;nf<4;nf++){
            #pragma unroll
            for(int r=0;r<4;r++){
                out[(size_t)(token + r)*EMBED + h*64 + nf*16 + lm] = f2bf(o_acc[mf][nf][r] * rl[r]);
            }
        }
    }
}

extern "C" void kernel_launch(void* const* d_in, const int* in_sizes, int n_in,
                              void* d_out, int out_size, void* d_ws, size_t ws_size,
                              hipStream_t stream) {
    const float* x      = (const float*)d_in[0];
    const float* g1     = (const float*)d_in[1];
    const float* b1     = (const float*)d_in[2];
    const float* g2     = (const float*)d_in[3];
    const float* b2     = (const float*)d_in[4];
    const float* w_qkv  = (const float*)d_in[5];
    const float* w_proj = (const float*)d_in[6];
    const float* b_proj = (const float*)d_in[7];
    const float* w_fc1  = (const float*)d_in[8];
    const float* b_fc1  = (const float*)d_in[9];
    const float* w_fc2  = (const float*)d_in[10];
    const float* b_fc2  = (const float*)d_in[11];
    float* out = (float*)d_out;

    char* ws = (char*)d_ws;
    // layout (bytes), total 102,236,160:
    u16*   wqkv_t  = (u16*)  (ws + 0);          //  2304x768 bf16 -> 3,538,944
    u16*   wproj_t = (u16*)  (ws + 3538944);    //   768x768 bf16 -> 1,179,648
    u16*   wfc1_t  = (u16*)  (ws + 4718592);    //  3072x768 bf16 -> 4,718,592
    u16*   wfc2_t  = (u16*)  (ws + 9437184);    //  768x3072 bf16 -> 4,718,592
    float* x1      = (float*)(ws + 14155776);   //  8192x768 fp32 -> 25,165,824
    u16*   hbuf    = (u16*)  (ws + 39321600);   //  8192x768 bf16 -> 12,582,912
    u16*   qkbuf   = (u16*)  (ws + 51904512);   // 8192x1536 bf16 -> 25,165,824
    u16*   vtbuf   = (u16*)  (ws + 77070336);   // 8x12x64x1024   -> 12,582,912
    u16*   attn_o  = (u16*)  (ws + 89653248);   //  8192x768 bf16 -> 12,582,912 (end 102,236,160)
    u16*   fc1_o   = qkbuf;  // alias: qk+vt+attn_o = 50,331,648 B exactly, lifetimes disjoint
    u16*   h2      = hbuf;   // alias: h dead after qkv GEMM

    dim3 tb(32, 8);
    transpose_cast<<<dim3(2304/32,  768/32), tb, 0, stream>>>(w_qkv,  wqkv_t,  768, 2304);
    transpose_cast<<<dim3( 768/32,  768/32), tb, 0, stream>>>(w_proj, wproj_t, 768,  768);
    transpose_cast<<<dim3(3072/32,  768/32), tb, 0, stream>>>(w_fc1,  wfc1_t,  768, 3072);
    transpose_cast<<<dim3( 768/32, 3072/32), tb, 0, stream>>>(w_fc2,  wfc2_t, 3072,  768);

    ln_kernel<<<TOKENS/4, 256, 0, stream>>>(x, g1, b1, hbuf);

    gemm_bt<3,128><<<dim3(2304/128, TOKENS/128), 256, 0, stream>>>(hbuf, wqkv_t, qkbuf, nullptr, nullptr, vtbuf, TOKENS, 2304, 768, 1536);

    attn_kernel<<<dim3(8, HEADS, BATCH), 256, 0, stream>>>(qkbuf, vtbuf, attn_o);

    gemm_bt<2,64><<<dim3( 768/128, TOKENS/64), 256, 0, stream>>>(attn_o, wproj_t, x1, b_proj, x, nullptr, TOKENS, 768, 768, 768);

    ln_kernel<<<TOKENS/4, 256, 0, stream>>>(x1, g2, b2, h2);

    gemm_bt<1,128><<<dim3(3072/128, TOKENS/128), 256, 0, stream>>>(h2, wfc1_t, fc1_o, b_fc1, nullptr, nullptr, TOKENS, 3072, 768, 3072);

    gemm_bt<2,64><<<dim3( 768/128, TOKENS/64), 256, 0, stream>>>(fc1_o, wfc2_t, out, b_fc2, x1, nullptr, TOKENS, 768, 3072, 768);
}

// Round 8
// 367.518 us; speedup vs baseline: 1.3163x; 1.0695x over previous
//
#include <hip/hip_runtime.h>
#include <hip/hip_bf16.h>
#include <math.h>

#define EMBED 768
#define HEADS 12
#define HEAD_DIM 64
#define HIDDEN 3072
#define SEQ 1024
#define BATCH 8
#define TOKENS (SEQ*BATCH)

typedef unsigned short u16;
typedef __attribute__((ext_vector_type(8))) short bf16x8;
typedef __attribute__((ext_vector_type(4))) float floatx4;
typedef __attribute__((ext_vector_type(4))) u16 u16x4;

__device__ __forceinline__ u16 f2bf(float f){
    union { float f; unsigned u; } v; v.f = f;
    unsigned r = v.u + 0x7fffu + ((v.u >> 16) & 1u);
    return (u16)(r >> 16);
}

__device__ __forceinline__ void gload16(const void* g, void* l){
    __builtin_amdgcn_global_load_lds((const __attribute__((address_space(1))) void*)g,
                                     (__attribute__((address_space(3))) void*)l, 16, 0, 0);
}

// fast GELU (tanh approx, sigmoid form): abs err ~1e-3, fine vs 0.109 threshold
__device__ __forceinline__ float gelu_fast(float x){
    float t = 1.5957691216f * (x + 0.044715f * x * x * x);
    return x / (1.0f + __expf(-t));
}

// ---------------- weight cast+transpose: W (K x N) fp32 -> Wt (N x K) bf16 ----------------
__global__ void transpose_cast(const float* __restrict__ W, u16* __restrict__ Wt, int K, int N){
    __shared__ float tile[32][33];
    int n0 = blockIdx.x * 32, k0 = blockIdx.y * 32;
    int tx = threadIdx.x, ty = threadIdx.y;  // 32 x 8
    #pragma unroll
    for(int i=0;i<32;i+=8) tile[ty+i][tx] = W[(size_t)(k0+ty+i)*N + n0+tx];
    __syncthreads();
    #pragma unroll
    for(int i=0;i<32;i+=8) Wt[(size_t)(n0+ty+i)*K + k0+tx] = f2bf(tile[tx][ty+i]);
}

// ---------------- layernorm: fp32 in -> bf16 out. one wave per row of 768 ----------------
__global__ __launch_bounds__(256) void ln_kernel(const float* __restrict__ x, const float* __restrict__ g,
                                                 const float* __restrict__ b, u16* __restrict__ out){
    int row  = blockIdx.x * 4 + (threadIdx.x >> 6);
    int lane = threadIdx.x & 63;
    const float* xr = x + (size_t)row * EMBED;
    float v[12];
    float s = 0.f;
    #pragma unroll
    for(int i=0;i<12;i++){ v[i] = xr[lane + i*64]; s += v[i]; }
    #pragma unroll
    for(int o=32;o>0;o>>=1) s += __shfl_xor(s, o);
    float mu = s * (1.0f/EMBED);
    float s2 = 0.f;
    #pragma unroll
    for(int i=0;i<12;i++){ float d = v[i]-mu; s2 += d*d; }
    #pragma unroll
    for(int o=32;o>0;o>>=1) s2 += __shfl_xor(s2, o);
    float rstd = rsqrtf(s2*(1.0f/EMBED) + 1e-5f);
    u16* orow = out + (size_t)row * EMBED;
    #pragma unroll
    for(int i=0;i<12;i++){
        int c = lane + i*64;
        orow[c] = f2bf((v[i]-mu)*rstd*g[c] + b[c]);
    }
}

// ---------------- GEMM: C(MxN) = A(MxK,bf16) @ Bt(NxK,bf16)^T ----------------
// Tiles: BM x 128, BK=64. LDS row-major [row][64 u16] (128B stride) with source-XOR swizzle.
// EPI 1: bias + fast GELU -> bf16.  EPI 2: bias + fp32 residual -> fp32.
// EPI 3 (BM=128): qkv: cols<1536 -> bf16 Cout (ldc=1536); cols>=1536 -> V transposed to vt.
template<int EPI, int BM>
__global__ __launch_bounds__(256) void gemm_bt(const u16* __restrict__ A, const u16* __restrict__ Bt,
        void* __restrict__ Cout, const float* __restrict__ bias, const float* __restrict__ res,
        u16* __restrict__ vt, int M, int N, int K, int ldc){
    constexpr int MF = BM/32;                    // m-frags per wave (4 for BM=128, 2 for BM=64)
    __shared__ __align__(16) u16 As[BM*64];      // BM rows x 64 u16
    __shared__ __align__(16) u16 Bs[128*64];     // 128 rows x 64 u16
    int tid  = threadIdx.x;
    int wave = tid >> 6, lane = tid & 63;
    int quad = lane >> 4, lm = lane & 15;
    int m0 = blockIdx.y * BM, n0 = blockIdx.x * 128;
    int wm = (wave & 1) * (BM/2);
    int wn = (wave >> 1) * 64;

    floatx4 acc[MF][4];
    #pragma unroll
    for(int i=0;i<MF;i++)
        #pragma unroll
        for(int j=0;j<4;j++) acc[i][j] = (floatx4){0.f,0.f,0.f,0.f};

    int srow = tid >> 3;                         // 0..31 staging row within 32-row panel
    int scol = ((tid & 7) ^ (srow & 7)) * 8;     // swizzled source chunk (u16 units)
    const u16* aP[MF];
    const u16* bP[4];
    #pragma unroll
    for(int p=0;p<MF;p++) aP[p] = A  + (size_t)(m0 + p*32 + srow) * K + scol;
    #pragma unroll
    for(int p=0;p<4;p++)  bP[p] = Bt + (size_t)(n0 + p*32 + srow) * K + scol;

    for(int k0=0; k0<K; k0+=64){
        __syncthreads();
        #pragma unroll
        for(int p=0;p<MF;p++) gload16(aP[p] + k0, As + p*2048 + tid*8);
        #pragma unroll
        for(int p=0;p<4;p++)  gload16(bP[p] + k0, Bs + p*2048 + tid*8);
        __syncthreads();
        #pragma unroll
        for(int ks=0;ks<2;ks++){
            int slotoff = (((ks*4+quad) ^ (lm&7)) << 3);
            bf16x8 af[MF], bfr[4];
            #pragma unroll
            for(int i=0;i<MF;i++)
                af[i]  = *(const bf16x8*)(As + (wm + i*16 + lm)*64 + slotoff);
            #pragma unroll
            for(int i=0;i<4;i++)
                bfr[i] = *(const bf16x8*)(Bs + (wn + i*16 + lm)*64 + slotoff);
            #pragma unroll
            for(int mf=0;mf<MF;mf++)
                #pragma unroll
                for(int nf=0;nf<4;nf++)
                    acc[mf][nf] = __builtin_amdgcn_mfma_f32_16x16x32_bf16(af[mf], bfr[nf], acc[mf][nf], 0, 0, 0);
        }
    }

    if(EPI == 3 && n0 >= 1536){
        // V columns -> vt[((b*12+h)*64+d)*1024 + key], 4 consecutive keys per 8B store
        #pragma unroll
        for(int nf=0;nf<4;nf++){
            int col = n0 + wn + nf*16 + lm;
            int hh = (col - 1536) >> 6;
            int d  = col & 63;
            #pragma unroll
            for(int mf=0;mf<MF;mf++){
                int row0 = m0 + wm + mf*16 + quad*4;
                int bb  = row0 >> 10;
                int key = row0 & 1023;
                u16x4 pk;
                #pragma unroll
                for(int r=0;r<4;r++) pk[r] = f2bf(acc[mf][nf][r]);
                *(u16x4*)(vt + ((size_t)(bb*HEADS+hh)*64 + d)*SEQ + key) = pk;
            }
        }
        return;
    }

    #pragma unroll
    for(int nf=0;nf<4;nf++){
        int col = n0 + wn + nf*16 + lm;
        float bv = bias ? bias[col] : 0.f;
        #pragma unroll
        for(int mf=0;mf<MF;mf++){
            int row0 = m0 + wm + mf*16 + quad*4;
            #pragma unroll
            for(int r=0;r<4;r++){
                float v = acc[mf][nf][r] + bv;
                size_t idx = (size_t)(row0 + r) * ldc + col;
                if(EPI == 1){
                    v = gelu_fast(v);
                    ((u16*)Cout)[idx] = f2bf(v);
                } else if(EPI == 2){
                    ((float*)Cout)[idx] = v + res[idx];
                } else {
                    ((u16*)Cout)[idx] = f2bf(v);
                }
            }
        }
    }
}

// ---------------- flash attention v4: S^T formulation ----------------
// qk: (TOKENS x 1536) bf16 [Q | K]; vt: [b][h][d][key] bf16; out: (TOKENS x 768) bf16.
// grid (8,12,8), block 256 = 4 waves; block: 128 q-rows; wave: 32 rows (2 qf-frags).
// St = K·Q^T (mfma(kf,qf)) -> C-layout has qrow=lm, key=kf*16+quad*4+r:
//   * softmax sum over keys = per-lane local sum + 2 cross-quad shfl (was 32 shfl)
//   * P write = 4 consecutive keys per lane -> 8 ds_write_b64 (was 32 ds_write_u16)
// P LDS: per-wave [32 rows][64 keys], chunk(4 u16) swizzle c^(2*(lm&7)) keeps b128 reads aligned.
__global__ __launch_bounds__(256) void attn_kernel(const u16* __restrict__ qk, const u16* __restrict__ vt,
                                                   u16* __restrict__ out){
    int qt = blockIdx.x, h = blockIdx.y, b = blockIdx.z;
    int tid = threadIdx.x;
    int wave = tid >> 6, lane = tid & 63;
    int quad = lane >> 4, lm = lane & 15;

    __shared__ __align__(16) u16 Ks[64*64];      // 8 KB
    __shared__ __align__(16) u16 Vs[64*64];      // 8 KB
    __shared__ __align__(16) u16 P[4*32*64];     // 16 KB, per-wave 32x64

    const u16* qbase = qk + (size_t)b * SEQ * 1536;
    const u16* vbase = vt + (size_t)(b*HEADS + h) * 64 * SEQ;
    u16* Pw = P + wave*2048;

    int q0 = qt*128 + wave*32;
    bf16x8 qf[2][2];
    #pragma unroll
    for(int qi=0;qi<2;qi++){
        const u16* qp = qbase + (size_t)(q0 + qi*16 + lm)*1536 + h*64;
        qf[qi][0] = *(const bf16x8*)(qp + quad*8);
        qf[qi][1] = *(const bf16x8*)(qp + 32 + quad*8);
    }

    float l_i[2] = {0.f, 0.f};
    floatx4 o_acc[2][4];
    #pragma unroll
    for(int qi=0;qi<2;qi++)
        #pragma unroll
        for(int nf=0;nf<4;nf++) o_acc[qi][nf] = (floatx4){0.f,0.f,0.f,0.f};

    int sr = lane >> 3;   // 0..7
    int sp = lane & 7;    // 0..7
    const float C = 0.18033688011112186f;  // 0.125 * log2(e)

    for(int kt=0; kt<16; kt++){
        __syncthreads();
        #pragma unroll
        for(int i=0;i<2;i++){
            int rr = wave*16 + i*8 + sr;
            int sw = (sp ^ (rr & 7)) * 8;
            gload16(qbase + (size_t)(kt*64 + rr)*1536 + 768 + h*64 + sw,
                    Ks + (wave*16 + i*8)*64 + lane*8);
            gload16(vbase + (size_t)rr*SEQ + kt*64 + sw,
                    Vs + (wave*16 + i*8)*64 + lane*8);
        }
        __syncthreads();

        // St = K Q^T : per wave 64 keys x 32 qrows. C-layout: qrow=lm, key=kf*16+quad*4+r.
        floatx4 s[4][2];
        #pragma unroll
        for(int kf=0;kf<4;kf++){
            int krow = kf*16 + lm;
            bf16x8 k0 = *(const bf16x8*)(Ks + krow*64 + ((quad     ^ (lm&7))*8));
            bf16x8 k1 = *(const bf16x8*)(Ks + krow*64 + (((4+quad) ^ (lm&7))*8));
            #pragma unroll
            for(int qi=0;qi<2;qi++){
                floatx4 t = (floatx4){0.f,0.f,0.f,0.f};
                t = __builtin_amdgcn_mfma_f32_16x16x32_bf16(k0, qf[qi][0], t, 0, 0, 0);
                t = __builtin_amdgcn_mfma_f32_16x16x32_bf16(k1, qf[qi][1], t, 0, 0, 0);
                s[kf][qi] = t;
            }
        }

        // softmax (fixed max) + P write
        #pragma unroll
        for(int qi=0;qi<2;qi++){
            float part = 0.f;
            #pragma unroll
            for(int kf=0;kf<4;kf++){
                #pragma unroll
                for(int r=0;r<4;r++){
                    float e = exp2f(s[kf][qi][r]*C);
                    s[kf][qi][r] = e;
                    part += e;
                }
            }
            part += __shfl_xor(part, 16);
            part += __shfl_xor(part, 32);
            l_i[qi] += part;
            #pragma unroll
            for(int kf=0;kf<4;kf++){
                u16x4 pk;
                #pragma unroll
                for(int r=0;r<4;r++) pk[r] = f2bf(s[kf][qi][r]);
                int c  = kf*4 + quad;                 // chunk (4 keys) 0..15
                int cp = c ^ (2*(lm & 7));            // even-XOR swizzle
                *(u16x4*)(Pw + (qi*16 + lm)*64 + cp*4) = pk;
            }
        }

        // O += P @ V
        #pragma unroll
        for(int ks=0;ks<2;ks++){
            bf16x8 vf[4];
            #pragma unroll
            for(int nf=0;nf<4;nf++)
                vf[nf] = *(const bf16x8*)(Vs + (nf*16+lm)*64 + (((ks*4+quad) ^ (lm&7))*8));
            #pragma unroll
            for(int qi=0;qi<2;qi++){
                int cr = (ks*8 + 2*quad) ^ (2*(lm & 7));
                bf16x8 pa = *(const bf16x8*)(Pw + (qi*16 + lm)*64 + cr*4);
                #pragma unroll
                for(int nf=0;nf<4;nf++)
                    o_acc[qi][nf] = __builtin_amdgcn_mfma_f32_16x16x32_bf16(pa, vf[nf], o_acc[qi][nf], 0, 0, 0);
            }
        }
    }

    #pragma unroll
    for(int qi=0;qi<2;qi++){
        float rl[4];
        #pragma unroll
        for(int r=0;r<4;r++) rl[r] = 1.0f / __shfl(l_i[qi], quad*4 + r);
        int token = b*SEQ + qt*128 + wave*32 + qi*16 + quad*4;
        #pragma unroll
        for(int nf=0;nf<4;nf++){
            #pragma unroll
            for(int r=0;r<4;r++){
                out[(size_t)(token + r)*EMBED + h*64 + nf*16 + lm] = f2bf(o_acc[qi][nf][r] * rl[r]);
            }
        }
    }
}

extern "C" void kernel_launch(void* const* d_in, const int* in_sizes, int n_in,
                              void* d_out, int out_size, void* d_ws, size_t ws_size,
                              hipStream_t stream) {
    const float* x      = (const float*)d_in[0];
    const float* g1     = (const float*)d_in[1];
    const float* b1     = (const float*)d_in[2];
    const float* g2     = (const float*)d_in[3];
    const float* b2     = (const float*)d_in[4];
    const float* w_qkv  = (const float*)d_in[5];
    const float* w_proj = (const float*)d_in[6];
    const float* b_proj = (const float*)d_in[7];
    const float* w_fc1  = (const float*)d_in[8];
    const float* b_fc1  = (const float*)d_in[9];
    const float* w_fc2  = (const float*)d_in[10];
    const float* b_fc2  = (const float*)d_in[11];
    float* out = (float*)d_out;

    char* ws = (char*)d_ws;
    // layout (bytes), total 102,236,160:
    u16*   wqkv_t  = (u16*)  (ws + 0);          //  2304x768 bf16 -> 3,538,944
    u16*   wproj_t = (u16*)  (ws + 3538944);    //   768x768 bf16 -> 1,179,648
    u16*   wfc1_t  = (u16*)  (ws + 4718592);    //  3072x768 bf16 -> 4,718,592
    u16*   wfc2_t  = (u16*)  (ws + 9437184);    //  768x3072 bf16 -> 4,718,592
    float* x1      = (float*)(ws + 14155776);   //  8192x768 fp32 -> 25,165,824
    u16*   hbuf    = (u16*)  (ws + 39321600);   //  8192x768 bf16 -> 12,582,912
    u16*   qkbuf   = (u16*)  (ws + 51904512);   // 8192x1536 bf16 -> 25,165,824
    u16*   vtbuf   = (u16*)  (ws + 77070336);   // 8x12x64x1024   -> 12,582,912
    u16*   attn_o  = (u16*)  (ws + 89653248);   //  8192x768 bf16 -> 12,582,912 (end 102,236,160)
    u16*   fc1_o   = qkbuf;  // alias: qk+vt+attn_o = 50,331,648 B exactly, lifetimes disjoint
    u16*   h2      = hbuf;   // alias: h dead after qkv GEMM

    dim3 tb(32, 8);
    transpose_cast<<<dim3(2304/32,  768/32), tb, 0, stream>>>(w_qkv,  wqkv_t,  768, 2304);
    transpose_cast<<<dim3( 768/32,  768/32), tb, 0, stream>>>(w_proj, wproj_t, 768,  768);
    transpose_cast<<<dim3(3072/32,  768/32), tb, 0, stream>>>(w_fc1,  wfc1_t,  768, 3072);
    transpose_cast<<<dim3( 768/32, 3072/32), tb, 0, stream>>>(w_fc2,  wfc2_t, 3072,  768);

    ln_kernel<<<TOKENS/4, 256, 0, stream>>>(x, g1, b1, hbuf);

    gemm_bt<3,128><<<dim3(2304/128, TOKENS/128), 256, 0, stream>>>(hbuf, wqkv_t, qkbuf, nullptr, nullptr, vtbuf, TOKENS, 2304, 768, 1536);

    attn_kernel<<<dim3(8, HEADS, BATCH), 256, 0, stream>>>(qkbuf, vtbuf, attn_o);

    gemm_bt<2,64><<<dim3( 768/128, TOKENS/64), 256, 0, stream>>>(attn_o, wproj_t, x1, b_proj, x, nullptr, TOKENS, 768, 768, 768);

    ln_kernel<<<TOKENS/4, 256, 0, stream>>>(x1, g2, b2, h2);

    gemm_bt<1,128><<<dim3(3072/128, TOKENS/128), 256, 0, stream>>>(h2, wfc1_t, fc1_o, b_fc1, nullptr, nullptr, TOKENS, 3072, 768, 3072);

    gemm_bt<2,64><<<dim3( 768/128, TOKENS/64), 256, 0, stream>>>(fc1_o, wfc2_t, out, b_fc2, x1, nullptr, TOKENS, 768, 3072, 768);
}